// Round 5
// baseline (87.531 us; speedup 1.0000x reference)
//
#include <hip/hip_runtime.h>

namespace {

constexpr int Bq = 32;    // batch
constexpr int Tq = 128;   // seq len == #scan steps (i) == softmax axis (t)
constexpr int Fq = 128;   // feature dim
constexpr int Uq = 128;   // unit dim
constexpr int PITCH  = 129;  // Xs pitch (odd -> conflict-free b32 row reads)
constexpr int APITCH = 20;   // As pitch
constexpr int CPITCH = 132;  // Cs pitch: 128 f + 4 pad (float4 16B-aligned)
constexpr int ITILE  = 8;    // i per block (1 per wave)

__device__ __forceinline__ float sigmoid_(float x) {
  return 1.0f / (1.0f + __expf(-x));
}
__device__ __forceinline__ float tanh_(float x) {
  x = fminf(20.0f, fmaxf(-20.0f, x));
  const float e = __expf(2.0f * x);
  return (e - 1.0f) / (e + 1.0f);
}

// ---------------------------------------------------------------------------
// Fully fused: logits -> softmax -> context -> gates -> activations.
//   L[t,i]  = sum_f X[b,t,f] * Wd[f,i]     (bd and carry s cancel in softmax)
//   alpha   = softmax_t(L)
//   C[i,f]  = sum_t alpha[t,i] * X[b,t,f]  (kept in LDS)
//   z       = C @ Wk + bl  (gates i,c,o only; f-gate dead: c0=0; Wr dead: h0=0)
//   out[b,i,u] = sig(z_o) * tanh( sig(z_i) * tanh(z_c) )
// grid(16, 32): x = i-tile (8 i), y = b.  512 threads = 8 waves.
// LDS 74.5 KB -> TWO blocks co-resident per CU (149 KB < 160 KB pool)
// = 4 waves/SIMD with INDEPENDENT barriers (blocks overlap each other's
// __syncthreads drains).  R4 was 2 waves/SIMD, single block/CU.
// ---------------------------------------------------------------------------
__global__ __launch_bounds__(512) void k_all(const float* __restrict__ X,
                                             const float* __restrict__ Wd,
                                             const float* __restrict__ Wk,
                                             const float* __restrict__ bl,
                                             float* __restrict__ out) {
  __shared__ float Xs[Tq * PITCH];                       // 66.0 KB
  __shared__ float SB[Tq * APITCH > ITILE * CPITCH ?     //  10.0 KB (union:
                      Tq * APITCH : ITILE * CPITCH];     //  As then Cs)
  float* As = SB;
  float* Cs = SB;
  const int tid = threadIdx.x;
  const int b = blockIdx.y;
  const int i0b = blockIdx.x * ITILE;

  // ---- stage X[b] into LDS (row t contiguous, pitch 129) ----
  const float* Xb = X + b * (Tq * Fq);
#pragma unroll
  for (int it = 0; it < 8; ++it) {
    const int e = tid + it * 512;
    const int t = e >> 5;                // 32 float4 per 128-float row
    const int f4 = e & 31;
    const float4 v = reinterpret_cast<const float4*>(Xb)[e];
    float* d = &Xs[t * PITCH + f4 * 4];
    d[0] = v.x; d[1] = v.y; d[2] = v.z; d[3] = v.w;
  }
  __syncthreads();

  const int lane = tid & 63;
  const int wv = tid >> 6;               // 0..7; wave owns i_local = wv
  const int i0 = __builtin_amdgcn_readfirstlane(i0b + wv);

  // ---- stage 1: logits for i0 at t = lane, lane+64 ----
  float a0 = 0.f, a1 = 0.f;
  const float* Wp = Wd + i0;             // Wd[f][i] at f*Tq + i (top F rows)
  const float* xr0 = &Xs[lane * PITCH];
  const float* xr1 = &Xs[(lane + 64) * PITCH];
#pragma unroll 16
  for (int f = 0; f < Fq; ++f) {
    const float w = Wp[f * Tq];          // uniform -> s_load (pipelined)
    a0 = fmaf(xr0[f], w, a0);
    a1 = fmaf(xr1[f], w, a1);
  }

  // ---- softmax over t (wave holds all 128 t) ----
  float m = fmaxf(a0, a1);
#pragma unroll
  for (int d = 1; d < 64; d <<= 1) m = fmaxf(m, __shfl_xor(m, d, 64));
  const float e0 = __expf(a0 - m);
  const float e1 = __expf(a1 - m);
  float s = e0 + e1;
#pragma unroll
  for (int d = 1; d < 64; d <<= 1) s += __shfl_xor(s, d, 64);
  const float inv = 1.0f / s;
  const float p0 = e0 * inv;
  const float p1 = e1 * inv;

  // ---- transpose alpha through LDS: As[t][wv] ----
  As[lane * APITCH + wv] = p0;
  As[(lane + 64) * APITCH + wv] = p1;
  __syncthreads();

  // ---- stage 2: C[wv][f] = sum_t alpha[t] * Xs[t][f]; lanes <-> f ----
  float c0 = 0.f, c1 = 0.f;
#pragma unroll 16
  for (int t = 0; t < Tq; ++t) {
    const float aa = As[t * APITCH + wv];   // wave-uniform -> LDS broadcast
    c0 = fmaf(aa, Xs[t * PITCH + lane], c0);
    c1 = fmaf(aa, Xs[t * PITCH + lane + 64], c1);
  }
  __syncthreads();  // As reads done before Cs overwrites the union buffer
  Cs[wv * CPITCH + lane] = c0;
  Cs[wv * CPITCH + lane + 64] = c1;
  __syncthreads();

  // ---- gate GEMM + activations.
  //      thread -> u = (wv&3)*32 + (lane&31);
  //                ig = (wv>>2)*2 + (lane>>5): rows ih = ig*2 .. +1 ----
  const int ub = (wv & 3) * 32 + (lane & 31);
  const int ih = (((wv >> 2) << 1) | (lane >> 5)) * 2;
  float zi[2] = {0.f, 0.f}, zc[2] = {0.f, 0.f}, zo[2] = {0.f, 0.f};

  const float* WkP = Wk + ub;            // Wk[f][n] at f*4U + n
  for (int f = 0; f < Fq; f += 4) {
    float4 cr[2];
#pragma unroll
    for (int j = 0; j < 2; ++j)          // b128 broadcast (2 addrs/wave: free)
      cr[j] = *reinterpret_cast<const float4*>(&Cs[(ih + j) * CPITCH + f]);
#pragma unroll
    for (int ff = 0; ff < 4; ++ff) {
      const float* wf = WkP + (f + ff) * (4 * Uq);
      const float wi = wf[0];            // coalesced dword loads (L2-resident)
      const float wc = wf[2 * Uq];
      const float wo = wf[3 * Uq];
#pragma unroll
      for (int j = 0; j < 2; ++j) {
        const float cv = (&cr[j].x)[ff];
        zi[j] = fmaf(cv, wi, zi[j]);
        zc[j] = fmaf(cv, wc, zc[j]);
        zo[j] = fmaf(cv, wo, zo[j]);
      }
    }
  }

  const float bi = bl[ub];
  const float bc = bl[2 * Uq + ub];
  const float bo = bl[3 * Uq + ub];
#pragma unroll
  for (int j = 0; j < 2; ++j) {
    const float cc = sigmoid_(zi[j] + bi) * tanh_(zc[j] + bc);
    const float h = sigmoid_(zo[j] + bo) * tanh_(cc);
    out[(b * Tq + i0b + ih + j) * Uq + ub] = h;
  }
}

}  // namespace

extern "C" void kernel_launch(void* const* d_in, const int* in_sizes, int n_in,
                              void* d_out, int out_size, void* d_ws, size_t ws_size,
                              hipStream_t stream) {
  const float* X  = (const float*)d_in[0];   // (B, T, F)
  const float* Wd = (const float*)d_in[1];   // (F+U, T); only rows [0,F) matter
  // d_in[2] = bd: constant along softmax axis -> cancels, unused
  const float* Wk = (const float*)d_in[3];   // (F, 4U)
  // d_in[4] = Wr: multiplied by h0 == 0 -> unused
  const float* bl = (const float*)d_in[5];   // (4U,)
  float* out = (float*)d_out;                // (B, T, U) fp32

  k_all<<<dim3(16, 32), 512, 0, stream>>>(X, Wd, Wk, bl, out);
}